// Round 1
// baseline (512.364 us; speedup 1.0000x reference)
//
#include <hip/hip_runtime.h>
#include <hip/hip_bf16.h>

#define HWv   35840   // H*W = 160*224
#define NPTS  35840   // query points per batch
#define Bv    2
#define Kv    16
#define Fv    16      // mid channels of weight net
#define CP3   67      // C+3
#define CPAD  68      // padded channel count
#define COUT  64
#define PPB   16      // points per block
#define NBLK_PER_B (NPTS / PPB)   // 2240

// ---------------- kernel 1: channel-last transpose of [xyz ; features] -------------
__global__ __launch_bounds__(256) void transpose_kernel(const float* __restrict__ xyz,
                                                        const float* __restrict__ feat,
                                                        float* __restrict__ feats_cl) {
    __shared__ float tile[CPAD][65];
    int t = threadIdx.x;
    int blk = blockIdx.x;                 // Bv * 560
    int b = blk / 560;
    int hw0 = (blk % 560) * 64;
    int j = t & 63, cq = t >> 6;          // 4 channels per iteration
    for (int cc = 0; cc < 17; ++cc) {
        int c = cc * 4 + cq;
        float v;
        if (c < 3)        v = xyz[((long)b * 3 + c) * HWv + hw0 + j];
        else if (c < CP3) v = feat[((long)b * 64 + (c - 3)) * HWv + hw0 + j];
        else              v = 0.f;
        tile[c][j] = v;
    }
    __syncthreads();
    int r = t >> 2, q = t & 3;
    float* dst = feats_cl + ((long)b * HWv + hw0 + r) * CPAD;
    #pragma unroll
    for (int i = q; i < 17; i += 4) {
        float4 v = make_float4(tile[i * 4 + 0][r], tile[i * 4 + 1][r],
                               tile[i * 4 + 2][r], tile[i * 4 + 3][r]);
        *(float4*)(dst + i * 4) = v;
    }
}

// ---------------- kernel 1b: pad w_lin [64][1072] -> [64][16][68] ------------------
__global__ __launch_bounds__(256) void wlpad_kernel(const float* __restrict__ w_lin,
                                                    float* __restrict__ wl_pad) {
    int e = blockIdx.x * 256 + threadIdx.x;   // 64*1088 = 69632 total
    if (e >= COUT * (Fv * CPAD)) return;
    int o = e / (Fv * CPAD);
    int r = e - o * (Fv * CPAD);
    int ff = r / CPAD;
    int c = r - ff * CPAD;
    wl_pad[e] = (c < CP3) ? w_lin[o * (Fv * CP3) + ff * CP3 + c] : 0.f;
}

// ---------------- kernel 2: fused gather + weightnet + agg + linear ----------------
__global__ __launch_bounds__(256) void pointconv_main(const float* __restrict__ feats_cl,
                                                      const float* __restrict__ wl_pad,
                                                      const int*   __restrict__ knn_idx,
                                                      const int*   __restrict__ mask,
                                                      const float* __restrict__ sampled,
                                                      const float* __restrict__ w1,
                                                      const float* __restrict__ b1,
                                                      const float* __restrict__ w2,
                                                      const float* __restrict__ b2,
                                                      const float* __restrict__ b_lin,
                                                      float* __restrict__ out) {
    __shared__ float4 sF[PPB][4][17];      // feats chunk: 16 pts x 4 k x 68ch  (17408 B)
    __shared__ float4 sW[8][Fv][17];       // w_lin chunk: 8 outs x 16 f x 68ch (34816 B)
    __shared__ float  sPart[PPB][Fv][9];   // reduction partials (9216 B, padded)
    __shared__ int    sRow[PPB][Kv];
    __shared__ float  sMask[PPB][Kv];
    __shared__ float  sNx[PPB][3];
    __shared__ float  sNet[240];           // w1(24) b1(8) w2(128) b2(16) b_lin(64)

    int t = threadIdx.x;
    int p = t >> 4, f = t & 15;
    int blk = blockIdx.x;
    int b = blk / NBLK_PER_B;
    int n0 = (blk % NBLK_PER_B) * PPB;

    { // per-(point, neighbor) gather metadata
        int pp = t >> 4, kk = t & 15;
        int n = n0 + pp;
        int base = (b * NPTS + n) * Kv + kk;
        int g = knn_idx[base];
        sRow[pp][kk]  = (b * HWv + g) * CPAD;
        sMask[pp][kk] = mask[base] ? 1.f : 0.f;
    }
    if (t < PPB * 3) { int pp = t / 3, c = t - pp * 3; sNx[pp][c] = sampled[(b * 3 + c) * HWv + n0 + pp]; }
    if (t < 240) {
        float v;
        if (t < 24)       v = w1[t];
        else if (t < 32)  v = b1[t - 24];
        else if (t < 160) v = w2[t - 32];
        else if (t < 176) v = b2[t - 160];
        else              v = b_lin[t - 176];
        sNet[t] = v;
    }
    __syncthreads();

    const float* W1 = sNet;       const float* B1 = sNet + 24;
    const float* W2 = sNet + 32;  const float* B2 = sNet + 160;
    const float* BL = sNet + 176;

    float4 agg[17];
    #pragma unroll
    for (int i = 0; i < 17; ++i) agg[i] = make_float4(0.f, 0.f, 0.f, 0.f);

    // ---- Phase A: gather + weight net + aggregation over K (4 chunks of 4) ----
    for (int kc = 0; kc < 4; ++kc) {
        {   // cooperative gather of 64 rows (16 pts x 4 k), 4 threads per row
            int r = t >> 2, q = t & 3;
            int pp = r >> 2, j = r & 3, k = kc * 4 + j;
            const float* src = feats_cl + sRow[pp][k];
            float mf = sMask[pp][k];
            #pragma unroll
            for (int i = q; i < 16; i += 4) {
                float4 v = *(const float4*)(src + i * 4);
                v.x *= mf; v.y *= mf; v.z *= mf; v.w *= mf;
                sF[pp][j][i] = v;
            }
            if (q == 0) {
                float4 v = *(const float4*)(src + 64);
                v.x *= mf; v.y *= mf; v.z *= mf; v.w *= mf;
                sF[pp][j][16] = v;
            }
        }
        __syncthreads();
        #pragma unroll
        for (int j = 0; j < 4; ++j) {
            const float* fp = (const float*)&sF[p][j][0];
            float r0 = fp[0] - sNx[p][0];
            float r1 = fp[1] - sNx[p][1];
            float r2 = fp[2] - sNx[p][2];
            float h[8];
            #pragma unroll
            for (int i = 0; i < 8; ++i) {
                float v = W1[i * 3] * r0 + W1[i * 3 + 1] * r1 + W1[i * 3 + 2] * r2 + B1[i];
                h[i] = v >= 0.f ? v : 0.1f * v;
            }
            float wk = B2[f];
            #pragma unroll
            for (int i = 0; i < 8; ++i) wk += W2[f * 8 + i] * h[i];
            wk = wk >= 0.f ? wk : 0.1f * wk;
            #pragma unroll
            for (int i = 0; i < 17; ++i) {
                float4 v = sF[p][j][i];
                agg[i].x += wk * v.x; agg[i].y += wk * v.y;
                agg[i].z += wk * v.z; agg[i].w += wk * v.w;
            }
        }
        __syncthreads();
    }

    // ---- Phase B: out[p][o] = sum_{f,c} agg * w_lin, o in chunks of 8 ----
    const float4* wlp4 = (const float4*)wl_pad;
    float4* sWlin = &sW[0][0][0];
    for (int oc = 0; oc < 8; ++oc) {
        for (int u = t; u < 8 * Fv * 17; u += 256) sWlin[u] = wlp4[oc * (8 * Fv * 17) + u];
        __syncthreads();
        float po[8];
        #pragma unroll
        for (int o = 0; o < 8; ++o) po[o] = 0.f;
        #pragma unroll
        for (int o = 0; o < 8; ++o) {
            #pragma unroll
            for (int i = 0; i < 17; ++i) {
                float4 wv = sW[o][f][i];
                po[o] += agg[i].x * wv.x + agg[i].y * wv.y + agg[i].z * wv.z + agg[i].w * wv.w;
            }
        }
        #pragma unroll
        for (int o = 0; o < 8; ++o) sPart[p][f][o] = po[o];
        __syncthreads();
        if (t < 128) {
            int pp = t >> 3, o8 = t & 7;
            float s = 0.f;
            #pragma unroll
            for (int ff = 0; ff < Fv; ++ff) s += sPart[pp][ff][o8];
            int o = oc * 8 + o8;
            s += BL[o];
            s = s >= 0.f ? s : 0.1f * s;
            out[((long)b * COUT + o) * HWv + n0 + pp] = s;
        }
        __syncthreads();
    }
}

extern "C" void kernel_launch(void* const* d_in, const int* in_sizes, int n_in,
                              void* d_out, int out_size, void* d_ws, size_t ws_size,
                              hipStream_t stream) {
    const float* xyz      = (const float*)d_in[0];
    const float* features = (const float*)d_in[1];
    const float* sampled  = (const float*)d_in[2];
    const int*   knn_idx  = (const int*)  d_in[3];
    const int*   mask     = (const int*)  d_in[4];
    const float* w1       = (const float*)d_in[5];
    const float* b1       = (const float*)d_in[6];
    const float* w2       = (const float*)d_in[7];
    const float* b2       = (const float*)d_in[8];
    const float* w_lin    = (const float*)d_in[9];
    const float* b_lin    = (const float*)d_in[10];
    float* out = (float*)d_out;

    // workspace layout
    float* feats_cl = (float*)d_ws;                                  // 2*35840*68*4 = 19,496,960 B
    float* wl_pad   = (float*)((char*)d_ws + (size_t)Bv * HWv * CPAD * 4);  // 278,528 B

    transpose_kernel<<<Bv * 560, 256, 0, stream>>>(xyz, features, feats_cl);
    wlpad_kernel<<<(COUT * Fv * CPAD + 255) / 256, 256, 0, stream>>>(w_lin, wl_pad);
    pointconv_main<<<Bv * NBLK_PER_B, 256, 0, stream>>>(feats_cl, wl_pad, knn_idx, mask,
                                                        sampled, w1, b1, w2, b2, b_lin, out);
}

// Round 2
// 232.044 us; speedup vs baseline: 2.2080x; 2.2080x over previous
//
#include <hip/hip_runtime.h>
#include <hip/hip_bf16.h>

#define HWv   35840   // H*W = 160*224
#define NPTS  35840
#define Bv    2
#define Kv    16
#define CP3   67
#define CPAD  80      // padded channel count (20 float4 chunks)
#define COUT  64
#define PPB   16      // points per block
#define NBLK_PER_B (NPTS / PPB)   // 2240
#define KDIM  1088    // 16 * 68  (f-major, c-minor, c padded to 68)
#define ASTR  1096    // agg LDS row stride in bf16 (548 dwords, %32==4)
#define WTSTR 264     // weight LDS p-stride in f32 (%32==8)

typedef __attribute__((ext_vector_type(4))) float  f32x4;
typedef __attribute__((ext_vector_type(8))) short  bf16x8;

static __device__ __forceinline__ unsigned short f2bf(float f) {
    unsigned int u = __float_as_uint(f);
    unsigned int r = (u + 0x7FFFu + ((u >> 16) & 1u)) >> 16;   // RNE
    return (unsigned short)r;
}

// ---------------- kernel 1: channel-last transpose of [xyz ; features], pad to 80 ----
__global__ __launch_bounds__(256) void transpose_kernel(const float* __restrict__ xyz,
                                                        const float* __restrict__ feat,
                                                        float* __restrict__ feats_cl) {
    __shared__ float tile[CPAD][65];
    int t = threadIdx.x;
    int blk = blockIdx.x;                 // Bv * 560
    int b = blk / 560;
    int hw0 = (blk % 560) * 64;
    int j = t & 63, cq = t >> 6;          // 4 channels per iteration
    for (int cc = 0; cc < 20; ++cc) {
        int c = cc * 4 + cq;
        float v = 0.f;
        if (c < 3)        v = xyz[((long)b * 3 + c) * HWv + hw0 + j];
        else if (c < CP3) v = feat[((long)b * 64 + (c - 3)) * HWv + hw0 + j];
        tile[c][j] = v;
    }
    __syncthreads();
    int r = t >> 2, q = t & 3;
    float* dst = feats_cl + ((long)b * HWv + hw0 + r) * CPAD;
    #pragma unroll
    for (int i = q; i < 20; i += 4) {
        float4 v = make_float4(tile[i * 4 + 0][r], tile[i * 4 + 1][r],
                               tile[i * 4 + 2][r], tile[i * 4 + 3][r]);
        *(float4*)(dst + i * 4) = v;
    }
}

// ---------------- kernel 1b: w_lin [64][1072] -> bf16 [64][1088] (f*68+c, c<68) ------
__global__ __launch_bounds__(256) void wl_bf16_kernel(const float* __restrict__ w_lin,
                                                      unsigned short* __restrict__ wl_bf) {
    int e = blockIdx.x * 256 + threadIdx.x;   // 64*1088 = 69632
    if (e >= COUT * KDIM) return;
    int o  = e / KDIM;
    int fc = e - o * KDIM;
    int f  = fc / 68;
    int c  = fc - f * 68;
    float v = (c < CP3) ? w_lin[o * (16 * CP3) + f * CP3 + c] : 0.f;
    wl_bf[e] = f2bf(v);
}

// ---------------- kernel 2: fused gather + weightnet + agg + MFMA linear -------------
__global__ __launch_bounds__(320, 2) void pointconv_main(
        const float*  __restrict__ feats_cl,
        const unsigned short* __restrict__ wl_bf,
        const int*    __restrict__ knn_idx,
        const int*    __restrict__ mask,
        const float*  __restrict__ sampled,
        const float*  __restrict__ w1,
        const float*  __restrict__ b1,
        const float*  __restrict__ w2,
        const float*  __restrict__ b2,
        const float*  __restrict__ b_lin,
        float*        __restrict__ out) {
    __shared__ float          sXyz[PPB][Kv][3];      // masked neighbor coords (3072 B)
    __shared__ float          sNx[PPB][3];           // query coords
    __shared__ int            sRow[PPB][Kv];         // gather row offsets (f32 elements)
    __shared__ float          sMask[PPB][Kv];
    __shared__ float          sNet[240];             // w1(24) b1(8) w2(128) b2(16) b_lin(64)
    __shared__ float          sWt[PPB * WTSTR];      // weights [p][k][f], p-stride 264 (16896 B)
    __shared__ unsigned short sAgg[PPB * ASTR];      // agg bf16 [p][f*68+c], stride 1096 (35072 B)

    int t = threadIdx.x;
    int blk = blockIdx.x;
    int b = blk / NBLK_PER_B;
    int n0 = (blk % NBLK_PER_B) * PPB;

    // ---- metadata ----
    if (t < 256) {
        int pp = t >> 4, kk = t & 15;
        int base = (b * NPTS + n0 + pp) * Kv + kk;
        int g = knn_idx[base];
        float mf = mask[base] ? 1.f : 0.f;
        int row = (b * HWv + g) * CPAD;
        sRow[pp][kk]  = row;
        sMask[pp][kk] = mf;
        sXyz[pp][kk][0] = feats_cl[row + 0] * mf;
        sXyz[pp][kk][1] = feats_cl[row + 1] * mf;
        sXyz[pp][kk][2] = feats_cl[row + 2] * mf;
    } else {
        int u = t - 256;                  // 0..63 (wave 4)
        for (int i = u; i < 240; i += 64) {
            float v;
            if (i < 24)       v = w1[i];
            else if (i < 32)  v = b1[i - 24];
            else if (i < 160) v = w2[i - 32];
            else if (i < 176) v = b2[i - 160];
            else              v = b_lin[i - 176];
            sNet[i] = v;
        }
        if (u < PPB * 3) { int pp = u / 3, c = u - pp * 3; sNx[pp][c] = sampled[(b * 3 + c) * HWv + n0 + pp]; }
    }
    __syncthreads();

    // ---- weight net: threads (p,f) over 16 k, write sWt[p][k][f] ----
    if (t < 256) {
        int p = t >> 4, f = t & 15;
        const float* W1 = sNet;
        const float* B1 = sNet + 24;
        const float* W2 = sNet + 32 + f * 8;
        float b2f = sNet[160 + f];
        float nx0 = sNx[p][0], nx1 = sNx[p][1], nx2 = sNx[p][2];
        for (int k = 0; k < Kv; ++k) {
            float r0 = sXyz[p][k][0] - nx0;
            float r1 = sXyz[p][k][1] - nx1;
            float r2 = sXyz[p][k][2] - nx2;
            float wk = b2f;
            #pragma unroll
            for (int i = 0; i < 8; ++i) {
                float v = W1[i * 3] * r0 + W1[i * 3 + 1] * r1 + W1[i * 3 + 2] * r2 + B1[i];
                v = v >= 0.f ? v : 0.1f * v;
                wk += W2[i] * v;
            }
            wk = wk >= 0.f ? wk : 0.1f * wk;
            sWt[p * WTSTR + k * 16 + f] = wk;
        }
    }
    __syncthreads();

    // ---- aggregation: threads (p,u), u in [0,20), own channels 4u..4u+3 ----
    {
        int p = t / 20, u = t - (t / 20) * 20;
        float agg[16][4];
        #pragma unroll
        for (int f = 0; f < 16; ++f)
            #pragma unroll
            for (int c = 0; c < 4; ++c) agg[f][c] = 0.f;

        for (int k = 0; k < Kv; ++k) {
            float mf = sMask[p][k];
            f32x4 fv = *(const f32x4*)(feats_cl + sRow[p][k] + u * 4);
            fv *= mf;
            const f32x4* wt4 = (const f32x4*)&sWt[p * WTSTR + k * 16];
            f32x4 w0 = wt4[0], w1v = wt4[1], w2v = wt4[2], w3v = wt4[3];
            #pragma unroll
            for (int c = 0; c < 4; ++c) {
                agg[0][c]  += w0[0] * fv[c];  agg[1][c]  += w0[1] * fv[c];
                agg[2][c]  += w0[2] * fv[c];  agg[3][c]  += w0[3] * fv[c];
                agg[4][c]  += w1v[0] * fv[c]; agg[5][c]  += w1v[1] * fv[c];
                agg[6][c]  += w1v[2] * fv[c]; agg[7][c]  += w1v[3] * fv[c];
                agg[8][c]  += w2v[0] * fv[c]; agg[9][c]  += w2v[1] * fv[c];
                agg[10][c] += w2v[2] * fv[c]; agg[11][c] += w2v[3] * fv[c];
                agg[12][c] += w3v[0] * fv[c]; agg[13][c] += w3v[1] * fv[c];
                agg[14][c] += w3v[2] * fv[c]; agg[15][c] += w3v[3] * fv[c];
            }
        }
        // write agg -> bf16 LDS  (only u<17 carry real channels 0..67)
        if (u < 17) {
            #pragma unroll
            for (int f = 0; f < 16; ++f) {
                ushort4 hv;
                hv.x = f2bf(agg[f][0]); hv.y = f2bf(agg[f][1]);
                hv.z = f2bf(agg[f][2]); hv.w = f2bf(agg[f][3]);
                *(ushort4*)&sAgg[p * ASTR + f * 68 + u * 4] = hv;
            }
        }
    }
    __syncthreads();

    // ---- Phase B: MFMA  out[16 pts][64 outs] = sAgg[16][1088] x wl_bf[64][1088]^T ----
    int w = t >> 6, l = t & 63;
    if (w < 4) {
        int row  = l & 15;        // A: point row  | B: output col
        int kgrp = l >> 4;        // k sub-block
        const bf16x8* aptr = (const bf16x8*)&sAgg[row * ASTR + kgrp * 8];
        const bf16x8* bptr = (const bf16x8*)(wl_bf + (w * 16 + row) * KDIM + kgrp * 8);
        f32x4 acc = {0.f, 0.f, 0.f, 0.f};
        for (int kt = 0; kt < KDIM / 32; ++kt) {           // 34 iters
            bf16x8 af = aptr[kt * 4];                      // +32 bf16 per iter
            bf16x8 bf_ = bptr[kt * 4];
            acc = __builtin_amdgcn_mfma_f32_16x16x32_bf16(af, bf_, acc, 0, 0, 0);
        }
        int o = w * 16 + row;
        float bias = sNet[176 + o];
        float* obase = out + ((long)(b * COUT + o)) * HWv + n0 + kgrp * 4;
        #pragma unroll
        for (int j = 0; j < 4; ++j) {                      // D row = pt = kgrp*4 + j
            float s = acc[j] + bias;
            s = s >= 0.f ? s : 0.1f * s;
            obase[j] = s;
        }
    }
}

extern "C" void kernel_launch(void* const* d_in, const int* in_sizes, int n_in,
                              void* d_out, int out_size, void* d_ws, size_t ws_size,
                              hipStream_t stream) {
    const float* xyz      = (const float*)d_in[0];
    const float* features = (const float*)d_in[1];
    const float* sampled  = (const float*)d_in[2];
    const int*   knn_idx  = (const int*)  d_in[3];
    const int*   mask     = (const int*)  d_in[4];
    const float* w1       = (const float*)d_in[5];
    const float* b1       = (const float*)d_in[6];
    const float* w2       = (const float*)d_in[7];
    const float* b2       = (const float*)d_in[8];
    const float* w_lin    = (const float*)d_in[9];
    const float* b_lin    = (const float*)d_in[10];
    float* out = (float*)d_out;

    // workspace: feats_cl f32 [2][35840][80] = 22,937,600 B ; wl_bf16 [64][1088]*2 = 139,264 B
    float* feats_cl = (float*)d_ws;
    unsigned short* wl_bf = (unsigned short*)((char*)d_ws + (size_t)Bv * HWv * CPAD * 4);

    transpose_kernel<<<Bv * 560, 256, 0, stream>>>(xyz, features, feats_cl);
    wl_bf16_kernel<<<(COUT * KDIM + 255) / 256, 256, 0, stream>>>(w_lin, wl_bf);
    pointconv_main<<<Bv * NBLK_PER_B, 320, 0, stream>>>(feats_cl, wl_bf, knn_idx, mask,
                                                        sampled, w1, b1, w2, b2, b_lin, out);
}

// Round 3
// 108.968 us; speedup vs baseline: 4.7020x; 2.1295x over previous
//
#include <hip/hip_runtime.h>
#include <hip/hip_bf16.h>

#define HWv   35840   // H*W = 160*224
#define NPTS  35840
#define Bv    2
#define Kv    16
#define CP3   67
#define COUT  64
#define PPB   16
#define NBLK_PER_B (NPTS / PPB)   // 2240
#define KDIM  1088    // 16 f * 68 c   (c: 0-63 features, 64-66 xyz, 67 pad)
#define ASTR  1096    // sAgg row stride (bf16 elems); 2192 B, 16B-aligned
#define WTSTR 264     // sWt p-stride in f32

typedef __attribute__((ext_vector_type(4))) float  f32x4;
typedef __attribute__((ext_vector_type(8))) short  bf16x8;

static __device__ __forceinline__ unsigned short f2bf(float f) {
    unsigned int u = __float_as_uint(f);
    unsigned int r = (u + 0x7FFFu + ((u >> 16) & 1u)) >> 16;   // RNE
    return (unsigned short)r;
}
static __device__ __forceinline__ float bf2f(unsigned short s) {
    return __uint_as_float((unsigned int)s << 16);
}
static __device__ __forceinline__ float leaky(float v) { return v >= 0.f ? v : 0.1f * v; }

// ---- kernel 1: channel-last bf16 features [B][HW][64] + f32 xyz [B][HW][4] ----
__global__ __launch_bounds__(256) void transpose_kernel(const float* __restrict__ xyz,
                                                        const float* __restrict__ feat,
                                                        unsigned short* __restrict__ feats_bf,
                                                        float* __restrict__ xyz_cl) {
    __shared__ float tile[68][65];
    int t = threadIdx.x;
    int blk = blockIdx.x;                 // Bv * 560
    int b = blk / 560;
    int hw0 = (blk % 560) * 64;
    int j = t & 63, cq = t >> 6;
    for (int cc = 0; cc < 17; ++cc) {
        int c = cc * 4 + cq;              // 0..67
        float v = 0.f;
        if (c < 64)      v = feat[((long)b * 64 + c) * HWv + hw0 + j];
        else if (c < 67) v = xyz[((long)b * 3 + (c - 64)) * HWv + hw0 + j];
        tile[c][j] = v;
    }
    __syncthreads();
    int r = t >> 2, q = t & 3;
    unsigned short* dst = feats_bf + ((long)b * HWv + hw0 + r) * 64;
    #pragma unroll
    for (int i = q; i < 16; i += 4) {
        ushort4 v;
        v.x = f2bf(tile[i * 4 + 0][r]); v.y = f2bf(tile[i * 4 + 1][r]);
        v.z = f2bf(tile[i * 4 + 2][r]); v.w = f2bf(tile[i * 4 + 3][r]);
        *(ushort4*)(dst + i * 4) = v;
    }
    if (q == 0) {
        float4 x4 = make_float4(tile[64][r], tile[65][r], tile[66][r], 0.f);
        *(float4*)(xyz_cl + ((long)b * HWv + hw0 + r) * 4) = x4;
    }
}

// ---- kernel 1b: w_lin -> bf16 [64][1088], channel-remapped to match sAgg ----
__global__ __launch_bounds__(256) void wl_bf16_kernel(const float* __restrict__ w_lin,
                                                      unsigned short* __restrict__ wl_bf) {
    int e = blockIdx.x * 256 + threadIdx.x;   // 64*1088 = 69632
    if (e >= COUT * KDIM) return;
    int o  = e / KDIM;
    int fc = e - o * KDIM;
    int f  = fc / 68;
    int c  = fc - f * 68;
    float v = 0.f;
    if (c < 64)      v = w_lin[o * (16 * CP3) + f * CP3 + 3 + c];   // feature channels
    else if (c < 67) v = w_lin[o * (16 * CP3) + f * CP3 + (c - 64)]; // xyz channels
    wl_bf[e] = f2bf(v);
}

// ---- kernel 2: fused gather + weightnet + agg + MFMA linear ----
__global__ __launch_bounds__(256, 4) void pointconv_main(
        const unsigned short* __restrict__ feats_bf,
        const float*  __restrict__ xyz_cl,
        const unsigned short* __restrict__ wl_bf,
        const int*    __restrict__ knn_idx,
        const int*    __restrict__ mask,
        const float*  __restrict__ sampled,
        const float*  __restrict__ w1,
        const float*  __restrict__ b1,
        const float*  __restrict__ w2,
        const float*  __restrict__ b2,
        const float*  __restrict__ b_lin,
        float*        __restrict__ out) {
    // lifetime-union region: [sXyz 3072 | sWt 16896] overlaid later by sAgg 35072
    __shared__ __align__(16) char sBuf[PPB * ASTR * 2];     // 35072 B
    __shared__ int   sRow[PPB][Kv];
    __shared__ float sMask[PPB][Kv];
    __shared__ float sNx[PPB][4];
    __shared__ float sNet[240];        // w1(24) b1(8) w2(128) b2(16) b_lin(64)

    float* sXyz = (float*)sBuf;                      // [p][k][3]
    float* sWt  = (float*)(sBuf + 3072);             // [p][k*16+f], p-stride 264
    unsigned short* sAgg = (unsigned short*)sBuf;    // [p][1096]

    int t = threadIdx.x;
    int blk = blockIdx.x;
    int b = blk / NBLK_PER_B;
    int n0 = (blk % NBLK_PER_B) * PPB;
    int p = t >> 4, u = t & 15;

    // ---- P0: metadata + params ----
    {
        int base = (b * NPTS + n0 + p) * Kv + u;
        int g = knn_idx[base];
        float mf = mask[base] ? 1.f : 0.f;
        int row = b * HWv + g;
        sRow[p][u]  = row * 128;                     // byte offset into feats_bf
        sMask[p][u] = mf;
        float4 x4 = *(const float4*)(xyz_cl + (long)row * 4);
        float* xd = sXyz + (p * Kv + u) * 3;
        xd[0] = x4.x * mf; xd[1] = x4.y * mf; xd[2] = x4.z * mf;
        if (t < 240) {
            float v;
            if (t < 24)       v = w1[t];
            else if (t < 32)  v = b1[t - 24];
            else if (t < 160) v = w2[t - 32];
            else if (t < 176) v = b2[t - 160];
            else              v = b_lin[t - 176];
            sNet[t] = v;
        }
        if (t < PPB * 3) { int pp = t / 3, c = t - pp * 3; sNx[pp][c] = sampled[(b * 3 + c) * HWv + n0 + pp]; }
    }
    __syncthreads();

    // ---- P1: weight net, thread = (p,k), h in registers ----
    {
        int k = u;
        const float* W1 = sNet;
        const float* B1 = sNet + 24;
        const float* W2 = sNet + 32;
        const float* B2 = sNet + 160;
        const float* xs = sXyz + (p * Kv + k) * 3;
        float r0 = xs[0] - sNx[p][0];
        float r1 = xs[1] - sNx[p][1];
        float r2 = xs[2] - sNx[p][2];
        float mf = sMask[p][k];
        float h[8];
        #pragma unroll
        for (int i = 0; i < 8; ++i)
            h[i] = leaky(W1[i * 3] * r0 + W1[i * 3 + 1] * r1 + W1[i * 3 + 2] * r2 + B1[i]);
        float wk[16];
        #pragma unroll
        for (int f = 0; f < 16; ++f) {
            float v = B2[f];
            #pragma unroll
            for (int i = 0; i < 8; ++i) v += W2[f * 8 + i] * h[i];
            wk[f] = leaky(v) * mf;                   // mask folded into weight
        }
        f32x4* wdst = (f32x4*)(sWt + p * WTSTR + k * 16);
        wdst[0] = (f32x4){wk[0], wk[1], wk[2], wk[3]};
        wdst[1] = (f32x4){wk[4], wk[5], wk[6], wk[7]};
        wdst[2] = (f32x4){wk[8], wk[9], wk[10], wk[11]};
        wdst[3] = (f32x4){wk[12], wk[13], wk[14], wk[15]};
    }
    __syncthreads();

    // ---- P2: aggregation. thread = (p,u); u owns feature channels 4u..4u+3 ----
    float agg[16][4];
    #pragma unroll
    for (int f = 0; f < 16; ++f)
        #pragma unroll
        for (int c = 0; c < 4; ++c) agg[f][c] = 0.f;
    float ax = 0.f, ay = 0.f, az = 0.f;              // xyz-channel agg (f = u role)

    for (int k = 0; k < Kv; ++k) {
        ushort4 hv = *(const ushort4*)((const char*)feats_bf + sRow[p][k] + u * 8);
        float fv0 = bf2f(hv.x), fv1 = bf2f(hv.y), fv2 = bf2f(hv.z), fv3 = bf2f(hv.w);
        const f32x4* wt4 = (const f32x4*)(sWt + p * WTSTR + k * 16);
        f32x4 w0 = wt4[0], w1v = wt4[1], w2v = wt4[2], w3v = wt4[3];
        #pragma unroll
        for (int c = 0; c < 4; ++c) {
            float fv = c == 0 ? fv0 : c == 1 ? fv1 : c == 2 ? fv2 : fv3;
            agg[0][c]  += w0[0] * fv;  agg[1][c]  += w0[1] * fv;
            agg[2][c]  += w0[2] * fv;  agg[3][c]  += w0[3] * fv;
            agg[4][c]  += w1v[0] * fv; agg[5][c]  += w1v[1] * fv;
            agg[6][c]  += w1v[2] * fv; agg[7][c]  += w1v[3] * fv;
            agg[8][c]  += w2v[0] * fv; agg[9][c]  += w2v[1] * fv;
            agg[10][c] += w2v[2] * fv; agg[11][c] += w2v[3] * fv;
            agg[12][c] += w3v[0] * fv; agg[13][c] += w3v[1] * fv;
            agg[14][c] += w3v[2] * fv; agg[15][c] += w3v[3] * fv;
        }
        // xyz channels: wt[p][k][f=u] * sXyz[p][k][*]
        float wtv = sWt[p * WTSTR + k * 16 + u];
        const float* xs = sXyz + (p * Kv + k) * 3;
        ax += wtv * xs[0]; ay += wtv * xs[1]; az += wtv * xs[2];
    }
    __syncthreads();      // all sWt/sXyz reads done; sAgg may now overlay

    // ---- write agg -> bf16 LDS ----
    {
        #pragma unroll
        for (int f = 0; f < 16; ++f) {
            ushort4 hv;
            hv.x = f2bf(agg[f][0]); hv.y = f2bf(agg[f][1]);
            hv.z = f2bf(agg[f][2]); hv.w = f2bf(agg[f][3]);
            *(ushort4*)&sAgg[p * ASTR + f * 68 + u * 4] = hv;
        }
        ushort4 hx;
        hx.x = f2bf(ax); hx.y = f2bf(ay); hx.z = f2bf(az); hx.w = 0;
        *(ushort4*)&sAgg[p * ASTR + u * 68 + 64] = hx;   // thread acts as f=u here
    }
    __syncthreads();

    // ---- P3: MFMA  out[16 pts][64 outs] = sAgg[16][1088] x wl_bf[64][1088]^T ----
    {
        int w = t >> 6, l = t & 63;
        int row  = l & 15;
        int kgrp = l >> 4;
        const bf16x8* aptr = (const bf16x8*)&sAgg[row * ASTR + kgrp * 8];
        const bf16x8* bptr = (const bf16x8*)(wl_bf + (w * 16 + row) * KDIM + kgrp * 8);
        f32x4 acc0 = {0.f, 0.f, 0.f, 0.f}, acc1 = {0.f, 0.f, 0.f, 0.f};
        #pragma unroll
        for (int kt = 0; kt < 17; ++kt)
            acc0 = __builtin_amdgcn_mfma_f32_16x16x32_bf16(aptr[kt * 4], bptr[kt * 4], acc0, 0, 0, 0);
        #pragma unroll
        for (int kt = 17; kt < 34; ++kt)
            acc1 = __builtin_amdgcn_mfma_f32_16x16x32_bf16(aptr[kt * 4], bptr[kt * 4], acc1, 0, 0, 0);
        f32x4 acc = acc0 + acc1;
        int o = w * 16 + row;
        float bias = sNet[176 + o];
        float4 res;
        res.x = leaky(acc[0] + bias);
        res.y = leaky(acc[1] + bias);
        res.z = leaky(acc[2] + bias);
        res.w = leaky(acc[3] + bias);
        *(float4*)(out + (long)(b * COUT + o) * HWv + n0 + kgrp * 4) = res;
    }
}

extern "C" void kernel_launch(void* const* d_in, const int* in_sizes, int n_in,
                              void* d_out, int out_size, void* d_ws, size_t ws_size,
                              hipStream_t stream) {
    const float* xyz      = (const float*)d_in[0];
    const float* features = (const float*)d_in[1];
    const float* sampled  = (const float*)d_in[2];
    const int*   knn_idx  = (const int*)  d_in[3];
    const int*   mask     = (const int*)  d_in[4];
    const float* w1       = (const float*)d_in[5];
    const float* b1       = (const float*)d_in[6];
    const float* w2       = (const float*)d_in[7];
    const float* b2       = (const float*)d_in[8];
    const float* w_lin    = (const float*)d_in[9];
    const float* b_lin    = (const float*)d_in[10];
    float* out = (float*)d_out;

    // workspace: feats_bf [2][35840][64] bf16 = 9,175,040 B ; xyz_cl [2][35840][4] f32 = 1,146,880 B ;
    //            wl_bf [64][1088] bf16 = 139,264 B
    unsigned short* feats_bf = (unsigned short*)d_ws;
    float* xyz_cl = (float*)((char*)d_ws + (size_t)Bv * HWv * 64 * 2);
    unsigned short* wl_bf = (unsigned short*)((char*)xyz_cl + (size_t)Bv * HWv * 4 * 4);

    transpose_kernel<<<Bv * 560, 256, 0, stream>>>(xyz, features, feats_bf, xyz_cl);
    wl_bf16_kernel<<<(COUT * KDIM + 255) / 256, 256, 0, stream>>>(w_lin, wl_bf);
    pointconv_main<<<Bv * NBLK_PER_B, 256, 0, stream>>>(feats_bf, xyz_cl, wl_bf, knn_idx, mask,
                                                        sampled, w1, b1, w2, b2, b_lin, out);
}